// Round 9
// baseline (880.562 us; speedup 1.0000x reference)
//
#include <hip/hip_runtime.h>
#include <cstdint>
#include <cstddef>

typedef __bf16 bf16x8 __attribute__((ext_vector_type(8)));
typedef float f32x4 __attribute__((ext_vector_type(4)));
typedef unsigned short u16;
typedef unsigned short u16x8 __attribute__((ext_vector_type(8)));

#define BATCH 4096
#define NE 8
#define NBLK 512   // physical grid: 512 blocks x 256 thr = 2 blocks/CU, co-resident

__device__ __forceinline__ u16 f2bf(float f) {
  union { float f; uint32_t u; } v; v.f = f;
  uint32_t u = v.u;
  u += 0x7fffu + ((u >> 16) & 1u);   // RTNE
  return (u16)(u >> 16);
}

__device__ __forceinline__ float bf2f(u16 u) {
  union { uint32_t u; float f; } v; v.u = ((uint32_t)u) << 16;
  return v.f;
}

__device__ __forceinline__ void cast8(const float* src, u16* dst) {
  const float4* p = (const float4*)src;
  float4 a = p[0], b = p[1];
  u16x8 o;
  o[0] = f2bf(a.x); o[1] = f2bf(a.y); o[2] = f2bf(a.z); o[3] = f2bf(a.w);
  o[4] = f2bf(b.x); o[5] = f2bf(b.y); o[6] = f2bf(b.z); o[7] = f2bf(b.w);
  *(u16x8*)dst = o;
}

// ---------------- software grid barrier (device-scope, self-resetting) -------
// Cooperative launch guarantees all NBLK blocks are co-resident (runtime
// validates; fails cleanly otherwise). Generation counter is monotonic across
// launches/graph-iterations; g_cnt is always 0 at kernel entry (invariant
// restored by the releasing block). __threadfence() = agent-scope fence
// (buffer_wbl2 + buffer_inv on gfx950) -> handles cross-XCD L2 non-coherence.
__device__ unsigned g_cnt = 0;
__device__ unsigned g_gen = 0;

__device__ __forceinline__ void gbar() {
  __syncthreads();                       // per-wave vmcnt drain + block sync
  if (threadIdx.x == 0) {
    __threadfence();                     // release: flush this XCD's L2
    unsigned my = __hip_atomic_load(&g_gen, __ATOMIC_RELAXED, __HIP_MEMORY_SCOPE_AGENT);
    unsigned old = __hip_atomic_fetch_add(&g_cnt, 1u, __ATOMIC_ACQ_REL, __HIP_MEMORY_SCOPE_AGENT);
    if (old == NBLK - 1u) {
      __hip_atomic_store(&g_cnt, 0u, __ATOMIC_RELAXED, __HIP_MEMORY_SCOPE_AGENT);
      __hip_atomic_fetch_add(&g_gen, 1u, __ATOMIC_RELEASE, __HIP_MEMORY_SCOPE_AGENT);
    } else {
      while (__hip_atomic_load(&g_gen, __ATOMIC_ACQUIRE, __HIP_MEMORY_SCOPE_AGENT) == my)
        __builtin_amdgcn_s_sleep(8);
    }
    __threadfence();                     // acquire: invalidate stale L2/L1 lines
  }
  __syncthreads();
}

// ---------------- phase bodies (verbatim r0 logic, de-kernelized) ------------

// W (E,N,K0) fp32 -> Bt (N, E*K0) bf16, one 8-elem chunk.
__device__ __forceinline__ void conv_w_chunk(const float* __restrict__ W,
                                             u16* __restrict__ Bt,
                                             int N, int K0, int chunk) {
  int per_row = K0 >> 3;
  int rid = chunk / per_row;             // rid = e*N + o
  int i0 = (chunk - rid * per_row) << 3;
  int e = rid / N;
  int o = rid - e * N;
  cast8(W + (size_t)rid * K0 + i0,
        Bt + (size_t)o * ((size_t)NE * K0) + (size_t)e * K0 + i0);
}

__device__ __forceinline__ void prep_chunk(const float* __restrict__ x,
                                           const float* __restrict__ W0,
                                           const float* __restrict__ W1,
                                           const float* __restrict__ W2,
                                           u16* __restrict__ h0, u16* __restrict__ Bt0,
                                           u16* __restrict__ Bt1, u16* __restrict__ Bt2,
                                           int t) {
  const int C0 = BATCH * 512 / 8;            // x cast:   262144
  const int C1 = C0 + NE * 1024 * 512 / 8;   // W0:      +524288
  const int C2 = C1 + NE * 1024 * 1024 / 8;  // W1:      +1048576
  if (t < C0) {
    cast8(x + (size_t)t * 8, h0 + (size_t)t * 8);
  } else if (t < C1) {
    conv_w_chunk(W0, Bt0, 1024, 512, t - C0);
  } else if (t < C2) {
    conv_w_chunk(W1, Bt1, 1024, 1024, t - C1);
  } else {
    conv_w_chunk(W2, Bt2, 512, 1024, t - C2);
  }
}

// out = [act](sum_s P_s + blend @ Bias), P_s bf16; bf16 or fp32 out.
template<int SLICES, bool ELU_ACT, bool OUT_BF16>
__device__ __forceinline__ void combine_chunk(const u16* __restrict__ P,
                                              const float* __restrict__ blend,
                                              const float* __restrict__ Bias,
                                              void* __restrict__ outp, int N, int t) {
  int per_row = N >> 3;
  int b = t / per_row;
  int i0 = (t - b * per_row) << 3;
  const size_t slice = (size_t)BATCH * N;
  float v[8] = {0, 0, 0, 0, 0, 0, 0, 0};
  #pragma unroll
  for (int s = 0; s < SLICES; ++s) {
    u16x8 pv = *(const u16x8*)(P + (size_t)s * slice + (size_t)b * N + i0);
    #pragma unroll
    for (int j = 0; j < 8; ++j) v[j] += bf2f(pv[j]);
  }
  const float4* blp = (const float4*)(blend + b * NE);
  float4 u0 = blp[0], u1 = blp[1];
  float bl[8] = {u0.x, u0.y, u0.z, u0.w, u1.x, u1.y, u1.z, u1.w};
  #pragma unroll
  for (int e = 0; e < NE; ++e) {
    const float4* bp = (const float4*)(Bias + (size_t)e * N + i0);
    float4 ba = bp[0], bb = bp[1];
    float bv[8] = {ba.x, ba.y, ba.z, ba.w, bb.x, bb.y, bb.z, bb.w};
    #pragma unroll
    for (int j = 0; j < 8; ++j) v[j] += bl[e] * bv[j];
  }
  if (ELU_ACT) {
    #pragma unroll
    for (int j = 0; j < 8; ++j) v[j] = v[j] > 0.f ? v[j] : expm1f(v[j]);
  }
  if (OUT_BF16) {
    u16x8 o;
    #pragma unroll
    for (int j = 0; j < 8; ++j) o[j] = f2bf(v[j]);
    *(u16x8*)((u16*)outp + (size_t)b * N + i0) = o;
  } else {
    float4* op = (float4*)((float*)outp + (size_t)b * N + i0);
    op[0] = (float4){v[0], v[1], v[2], v[3]};
    op[1] = (float4){v[4], v[5], v[6], v[7]};
  }
}

#define GL2LDS(g, l) __builtin_amdgcn_global_load_lds( \
    (__attribute__((address_space(1))) void*)(g),      \
    (__attribute__((address_space(3))) void*)(l), 16, 0, 0)

// Expert-folding GEMM phase (r0-verbatim): P_z(M x N) = sum_{e in slice z}
// blend[:,e]*(h @ W_e^T). BM=BN=128, BK=64, 4 waves (2x2), XOR-8 LDS swizzle
// (0 conflicts), transposed coalesced bf16 epilogue. Per expert: fresh acc2
// over K0, then fold acc += blend[row,e]*acc2. SMEM: Hs 16K | Bs 16K | bls 4.6K.
template<int K0, int EPB>
__device__ __forceinline__ void gemm_fold_phase(char* SMEM,
    const u16* __restrict__ h, const u16* __restrict__ Bt,
    const float* __restrict__ blend, u16* __restrict__ P, int N,
    int bx, int by, int bz) {
  u16* Hs   = (u16*)SMEM;                 // 128 x 64 bf16
  u16* Bs   = (u16*)(SMEM + 16384);       // 128 x 64 bf16
  float* bls = (float*)(SMEM + 32768);    // 128 x 9

  const int tid  = threadIdx.x;
  const int w    = tid >> 6, lane = tid & 63;
  const int wm   = w >> 1,   wn   = w & 1;
  const int lrow = lane & 15, quad = lane >> 4;

  const int row0 = bx * 128;
  const int col0 = by * 128;
  const int e0   = bz * EPB;
  const int EK   = K0 * NE;

  // stage blend[row0..row0+127, 0..7] into bls (vector read, scalar writes)
  {
    const float4 bv = ((const float4*)(blend + (size_t)row0 * NE))[tid];
    int row = tid >> 1, c0 = (tid & 1) * 4;
    bls[row * 9 + c0 + 0] = bv.x;
    bls[row * 9 + c0 + 1] = bv.y;
    bls[row * 9 + c0 + 2] = bv.z;
    bls[row * 9 + c0 + 3] = bv.w;
  }

  // staging addresses (XOR-8 swizzle on the global side)
  const int trow = tid >> 3;
  const int tcol = (tid & 7) ^ (trow & 7);
  const u16* gH = h + (size_t)(row0 + trow) * K0 + (tcol << 3);
  const u16* gB = Bt + (size_t)(col0 + trow) * EK + (size_t)e0 * K0 + (tcol << 3);
  u16* lH = &Hs[tid * 8];
  u16* lB = &Bs[tid * 8];

  // fragment read pointers
  const int xr = lrow & 7;
  const u16* fH[2][4];
  const u16* fB[2][4];
  #pragma unroll
  for (int kc = 0; kc < 2; ++kc)
    #pragma unroll
    for (int i = 0; i < 4; ++i) {
      fH[kc][i] = &Hs[(wm * 64 + i * 16 + lrow) * 64 + (((kc * 4 + quad) ^ xr) << 3)];
      fB[kc][i] = &Bs[(wn * 64 + i * 16 + lrow) * 64 + (((kc * 4 + quad) ^ xr) << 3)];
    }

  f32x4 acc[4][4];
  #pragma unroll
  for (int i = 0; i < 4; ++i)
    #pragma unroll
    for (int j = 0; j < 4; ++j) acc[i][j] = (f32x4){0.f, 0.f, 0.f, 0.f};

  #pragma unroll 1
  for (int ee = 0; ee < EPB; ++ee) {
    f32x4 acc2[4][4];
    #pragma unroll
    for (int i = 0; i < 4; ++i)
      #pragma unroll
      for (int j = 0; j < 4; ++j) acc2[i][j] = (f32x4){0.f, 0.f, 0.f, 0.f};

    const u16* pH = gH;
    const u16* pB = gB + (size_t)ee * K0;

    for (int it = 0; it < K0 / 64; ++it) {
      #pragma unroll
      for (int i = 0; i < 4; ++i) {
        GL2LDS(pH + (size_t)(32 * i) * K0, lH + 2048 * i);
        GL2LDS(pB + (size_t)(32 * i) * EK, lB + 2048 * i);
      }
      pH += 64; pB += 64;
      __syncthreads();

      #pragma unroll
      for (int kc = 0; kc < 2; ++kc) {
        bf16x8 hf[4], bfr[4];
        #pragma unroll
        for (int i = 0; i < 4; ++i) hf[i] = *(const bf16x8*)fH[kc][i];
        #pragma unroll
        for (int j = 0; j < 4; ++j) bfr[j] = *(const bf16x8*)fB[kc][j];
        #pragma unroll
        for (int i = 0; i < 4; ++i)
          #pragma unroll
          for (int j = 0; j < 4; ++j)
            acc2[i][j] = __builtin_amdgcn_mfma_f32_16x16x32_bf16(hf[i], bfr[j], acc2[i][j], 0, 0, 0);
      }
      __syncthreads();
    }

    // fold: acc += blend[row, e0+ee] * acc2 (row = wm*64 + mt*16 + quad*4 + r)
    #pragma unroll
    for (int mt = 0; mt < 4; ++mt) {
      float bl[4];
      #pragma unroll
      for (int r = 0; r < 4; ++r)
        bl[r] = bls[(wm * 64 + mt * 16 + quad * 4 + r) * 9 + (e0 + ee)];
      #pragma unroll
      for (int nt = 0; nt < 4; ++nt)
        #pragma unroll
        for (int r = 0; r < 4; ++r)
          acc[mt][nt][r] += bl[r] * acc2[mt][nt][r];
    }
  }

  // Coalesced epilogue via per-wave LDS transpose (Hs free after final barrier;
  // each wave uses its private 4 KB segment). C/D: col=lane&15, row=quad*4+reg.
  u16* Ps = P + (size_t)bz * ((size_t)BATCH * N);
  u16* ls = &Hs[w * 2048];   // 32 rows x 64 cols u16 per wave
  #pragma unroll
  for (int half = 0; half < 2; ++half) {
    #pragma unroll
    for (int mh = 0; mh < 2; ++mh) {
      int mt = half * 2 + mh;
      #pragma unroll
      for (int r = 0; r < 4; ++r) {
        int rloc = mh * 16 + quad * 4 + r;          // 0..31
        #pragma unroll
        for (int nt = 0; nt < 4; ++nt) {
          int col = nt * 16 + lrow;                 // 0..63
          int c8 = (col >> 3) ^ (rloc & 7);         // XOR-8 chunk swizzle
          ls[rloc * 64 + (c8 << 3) + (col & 7)] = f2bf(acc[mt][nt][r]);
        }
      }
    }
    #pragma unroll
    for (int p = 0; p < 4; ++p) {
      int rloc = p * 8 + (lane >> 3);               // 0..31
      int c8 = (lane & 7) ^ (rloc & 7);
      u16x8 v = *(const u16x8*)&ls[rloc * 64 + (c8 << 3)];
      int row = row0 + wm * 64 + half * 32 + rloc;
      int colg = col0 + wn * 64 + ((lane & 7) << 3);
      *(u16x8*)&Ps[(size_t)row * N + colg] = v;
    }
  }
}

// ---------------- the fused persistent kernel --------------------------------
// 7 r0-dispatches -> 1 dispatch + 6 device barriers (saves ~15 us per removed
// dispatch boundary; r1..r7 dispatch-sum vs dur_us gap is ~95-105 us constant).
__global__ __launch_bounds__(256, 2)
void fused_kernel(const float* __restrict__ blend, const float* __restrict__ x,
                  const float* __restrict__ W0, const float* __restrict__ B0,
                  const float* __restrict__ W1, const float* __restrict__ B1,
                  const float* __restrict__ W2, const float* __restrict__ B2,
                  float* __restrict__ out, char* __restrict__ ws) {
  __shared__ __align__(16) char SMEM[37376];   // Hs 16K | Bs 16K | bls 4.6K

  u16* hA  = (u16*)ws;                           // h0 (4096x512) then h2 (4096x1024)
  u16* h1  = (u16*)(ws + 8388608);               // 4096x1024 bf16
  u16* Bt0 = (u16*)(ws + 16777216);              // 1024 x 4096 bf16
  u16* Bt1 = (u16*)(ws + 25165824);              // 1024 x 8192 bf16
  u16* Bt2 = (u16*)(ws + 41943040);              // 512 x 8192 bf16
  u16* P   = (u16*)(ws + 50331648);              // bf16 partials

  const int bid = blockIdx.x;
  const int tid = threadIdx.x;

  // phase 0: prep (logical 9216 blocks -> 18 iters/block)
  for (int i = bid; i < 9216; i += NBLK)
    prep_chunk(x, W0, W1, W2, hA, Bt0, Bt1, Bt2, i * 256 + tid);
  gbar();

  // phase 1: layer-0 GEMM, grid (32,8,2) == 512
  gemm_fold_phase<512, 4>(SMEM, hA, Bt0, blend, P, 1024,
                          bid & 31, (bid >> 5) & 7, bid >> 8);
  gbar();

  // phase 2: layer-0 combine (2048 logical -> 4 iters), bias+ELU, bf16 h1
  for (int i = bid; i < 2048; i += NBLK)
    combine_chunk<2, true, true>(P, blend, B0, h1, 1024, i * 256 + tid);
  gbar();

  // phase 3: layer-1 GEMM, grid (32,8,2) == 512
  gemm_fold_phase<1024, 4>(SMEM, h1, Bt1, blend, P, 1024,
                           bid & 31, (bid >> 5) & 7, bid >> 8);
  gbar();

  // phase 4: layer-1 combine -> hA (h2)
  for (int i = bid; i < 2048; i += NBLK)
    combine_chunk<2, true, true>(P, blend, B1, hA, 1024, i * 256 + tid);
  gbar();

  // phase 5: layer-2 GEMM, grid (32,4,4) == 512, N=512
  gemm_fold_phase<1024, 2>(SMEM, hA, Bt2, blend, P, 512,
                           bid & 31, (bid >> 5) & 3, bid >> 7);
  gbar();

  // phase 6: layer-2 combine (1024 logical -> 2 iters), linear, fp32 out
  for (int i = bid; i < 1024; i += NBLK)
    combine_chunk<4, false, false>(P, blend, B2, out, 512, i * 256 + tid);
}

extern "C" void kernel_launch(void* const* d_in, const int* in_sizes, int n_in,
                              void* d_out, int out_size, void* d_ws, size_t ws_size,
                              hipStream_t stream) {
  const float* blend = (const float*)d_in[0];
  const float* x  = (const float*)d_in[1];
  const float* W0 = (const float*)d_in[2];
  const float* B0 = (const float*)d_in[3];
  const float* W1 = (const float*)d_in[4];
  const float* B1 = (const float*)d_in[5];
  const float* W2 = (const float*)d_in[6];
  const float* B2 = (const float*)d_in[7];
  float* out = (float*)d_out;
  char* wsp  = (char*)d_ws;

  // Cooperative launch: runtime GUARANTEES all 512 blocks co-resident (or
  // fails cleanly) — the sanctioned mechanism for grid-wide sync (G16).
  void* args[] = {&blend, &x, &W0, &B0, &W1, &B1, &W2, &B2, &out, &wsp};
  hipError_t err = hipLaunchCooperativeKernel((const void*)fused_kernel,
                                              dim3(NBLK), dim3(256),
                                              args, 0, stream);
  if (err != hipSuccess) {
    // Fallback: plain launch (2 blocks/CU fit by capacity: 74.8 KB LDS < 160 KB,
    // VGPR <= 128 via launch_bounds; CP places all blocks greedily at t=0).
    fused_kernel<<<NBLK, 256, 0, stream>>>(blend, x, W0, B0, W1, B1, W2, B2,
                                           out, wsp);
  }
}